// Round 6
// baseline (831.831 us; speedup 1.0000x reference)
//
#include <hip/hip_runtime.h>

#define EMBD 300
#define NSTEP 300
#define HID 512
#define G4 2048
#define TPB 256
#define NWG 32

#define TS2 15              // steps per phase-1 step-group
#define NSG 20              // step groups (20*15 = 300)
#define NRG 8               // row groups (8*256 = 2048 rows)

#define SENTINEL 0xFFC00000u              // quiet NaN: h values are always finite
#define SENT64   0xFFC00000FFC00000ull

// ws float layout:
//   [0 .. 614400)      : X_proj [300][2048]
//   [614400 .. +154112): HSEQ [301][512]  (h state before each step)
#define XP_SZ    (NSTEP * G4)
#define HSEQ_OFF XP_SZ

__device__ __forceinline__ float fsig(float x) { return 1.0f / (1.0f + __expf(-x)); }
__device__ __forceinline__ float ftanh(float x) {
    x = fminf(15.0f, fmaxf(-15.0f, x));
    float t = __expf(2.0f * x);
    return (t - 1.0f) / (t + 1.0f);
}

// Pipelined poll of one 8-byte slot (agent-class sc0 sc1 loads, 4 in flight).
// The slot transitions atomically SENT64 -> final (producer uses one aligned
// 8B store), so a single u64 compare detects it. Exits only when ALL lanes
// of the wave have non-sentinel data (s_cbranch_vccz on eq-compare), which is
// monotone -> no divergence hazard. Drains vmcnt before returning so the
// rotation registers are dead at exit (~1 rotation, not an RTT).
__device__ __forceinline__ unsigned long long poll8_pipe(const void* p,
                                                         unsigned long long sen) {
    unsigned long long r0, r1, r2, r3;
    asm volatile(
        "global_load_dwordx2 %[r0], %[ad], off sc0 sc1\n\t"
        "global_load_dwordx2 %[r1], %[ad], off sc0 sc1\n\t"
        "global_load_dwordx2 %[r2], %[ad], off sc0 sc1\n\t"
        "global_load_dwordx2 %[r3], %[ad], off sc0 sc1\n"
        "LP%=:\n\t"
        "s_waitcnt vmcnt(3)\n\t"
        "v_cmp_eq_u64 vcc, %[sn], %[r0]\n\t"
        "s_cbranch_vccz G0%=\n\t"
        "global_load_dwordx2 %[r0], %[ad], off sc0 sc1\n\t"
        "s_waitcnt vmcnt(3)\n\t"
        "v_cmp_eq_u64 vcc, %[sn], %[r1]\n\t"
        "s_cbranch_vccz G1%=\n\t"
        "global_load_dwordx2 %[r1], %[ad], off sc0 sc1\n\t"
        "s_waitcnt vmcnt(3)\n\t"
        "v_cmp_eq_u64 vcc, %[sn], %[r2]\n\t"
        "s_cbranch_vccz G2%=\n\t"
        "global_load_dwordx2 %[r2], %[ad], off sc0 sc1\n\t"
        "s_waitcnt vmcnt(3)\n\t"
        "v_cmp_eq_u64 vcc, %[sn], %[r3]\n\t"
        "s_cbranch_vccz G3%=\n\t"
        "global_load_dwordx2 %[r3], %[ad], off sc0 sc1\n\t"
        "s_branch LP%=\n"
        "G3%=:\n\t"
        "v_lshlrev_b64 %[r0], 0, %[r3]\n\t"
        "s_branch GE%=\n"
        "G2%=:\n\t"
        "v_lshlrev_b64 %[r0], 0, %[r2]\n\t"
        "s_branch GE%=\n"
        "G1%=:\n\t"
        "v_lshlrev_b64 %[r0], 0, %[r1]\n"
        "GE%=:\n"
        "G0%=:\n\t"
        "s_waitcnt vmcnt(0)"
        : [r0] "=&v"(r0), [r1] "=&v"(r1), [r2] "=&v"(r2), [r3] "=&v"(r3)
        : [ad] "v"(p), [sn] "v"(sen)
        : "vcc", "memory");
    return r0;
}

// Phase 1: X_proj[t][r] = b_ih[r]+b_hh[r] + sum_e W_ih[r][e]*emb[x[t]][e]
// Grid (NRG, NSG). rowg==0 blocks sentinel-clear HSEQ rows t0+1..t0+15;
// (0,0) also copies h0 into HSEQ[0]. Re-done every call -> replay-safe.
__global__ __launch_bounds__(TPB) void xproj_init_kernel(
    const int* __restrict__ x, const float* __restrict__ h0,
    const float* __restrict__ emb, const float* __restrict__ W_ih,
    const float* __restrict__ b_ih, const float* __restrict__ b_hh,
    float* __restrict__ ws) {
    const int rowg = blockIdx.x;      // 0..7
    const int sg   = blockIdx.y;      // 0..19
    const int tid  = threadIdx.x;
    const int t0   = sg * TS2;
    const int r    = rowg * TPB + tid;

    float* hseq = ws + HSEQ_OFF;

    if (rowg == 0) {
        unsigned* hs = (unsigned*)(hseq + (size_t)(t0 + 1) * HID);
        for (int i = tid; i < TS2 * HID; i += TPB) hs[i] = SENTINEL;
        if (sg == 0) {
            for (int i = tid; i < HID; i += TPB) hseq[i] = h0[i];
        }
    }

    __shared__ float e_lds[TS2][EMBD];
    for (int tt = 0; tt < TS2; ++tt) {
        const float* er = emb + (long long)x[t0 + tt] * EMBD;
        for (int i = tid; i < EMBD; i += TPB) e_lds[tt][i] = er[i];
    }
    __syncthreads();

    float acc[TS2];
    const float bsum = b_ih[r] + b_hh[r];
    #pragma unroll
    for (int tt = 0; tt < TS2; ++tt) acc[tt] = bsum;

    const float* wrow = W_ih + (size_t)r * EMBD;
    for (int e = 0; e < EMBD; e += 4) {
        const float4 w4 = *(const float4*)(wrow + e);
        #pragma unroll
        for (int tt = 0; tt < TS2; ++tt) {
            acc[tt] = fmaf(w4.x, e_lds[tt][e],     acc[tt]);
            acc[tt] = fmaf(w4.y, e_lds[tt][e + 1], acc[tt]);
            acc[tt] = fmaf(w4.z, e_lds[tt][e + 2], acc[tt]);
            acc[tt] = fmaf(w4.w, e_lds[tt][e + 3], acc[tt]);
        }
    }
    #pragma unroll
    for (int tt = 0; tt < TS2; ++tt)
        ws[(size_t)(t0 + tt) * G4 + r] = acc[tt];
}

// Phase 2: 32-WG persistent dataflow scan, pipelined data-as-flag polling.
// Each thread polls its own 8B pair of HSEQ[s]; producers publish adjacent
// h pairs with single atomic 8B agent-scope stores. One __syncthreads per
// step (fill -> compute); the end-of-step barrier is unnecessary because the
// LDS overwrite for step s+1 is ordered after all step-s LDS reads through
// the shfl -> producer-store -> detect dependence chain.
__global__ __launch_bounds__(TPB, 1) void lstm_scan_kernel(
    const float* __restrict__ c0, const float* __restrict__ W_hh,
    const float* __restrict__ fc_w, const float* __restrict__ fc_b,
    float* __restrict__ ws, float* __restrict__ out) {
    const int tid  = threadIdx.x;
    const int wg   = blockIdx.x;
    const int v    = tid >> 6;     // wave id
    const int lane = tid & 63;
    const int g    = lane >> 4;    // group within wave
    const int li   = lane & 15;    // lane within group (column split)
    const int hidx = wg * 16 + v * 4 + g;

    float* hseq     = ws + HSEQ_OFF;        // [301][512]
    const float* xp = ws;                   // [300][2048]

    __shared__ __align__(16) float h_lds[576];   // idx i -> i + 4*(i>>5)

    // W_hh slice in registers: wreg[gate][k] = W_hh[gate*512 + hidx][li*32 + k]
    float wreg[4][32];
    #pragma unroll
    for (int gate = 0; gate < 4; ++gate) {
        const float* wr = W_hh + ((size_t)gate * HID + hidx) * HID + li * 32;
        #pragma unroll
        for (int k = 0; k < 32; k += 4) {
            const float4 w4 = *(const float4*)(wr + k);
            wreg[gate][k] = w4.x; wreg[gate][k + 1] = w4.y;
            wreg[gate][k + 2] = w4.z; wreg[gate][k + 3] = w4.w;
        }
    }

    const bool upd = (li == 0);
    float c = upd ? c0[hidx] : 0.0f;

    for (int s = 0; s < NSTEP; ++s) {
        // X_proj loads issued before the poll -> latency hidden under it.
        float xi = 0.f, xf = 0.f, xg = 0.f, xo = 0.f;
        if (upd) {
            const float* xpt = xp + (size_t)s * G4 + hidx;
            xi = xpt[0]; xf = xpt[HID]; xg = xpt[2 * HID]; xo = xpt[3 * HID];
        }

        // Pipelined poll of this thread's 8B pair of HSEQ[s].
        const unsigned long long hv =
            poll8_pipe((const float*)hseq + (size_t)s * HID + 2 * tid, SENT64);
        {
            const int i0 = 2 * tid;
            float2* dst = (float2*)&h_lds[i0 + ((i0 >> 5) << 2)];
            *dst = make_float2(__uint_as_float((unsigned)hv),
                               __uint_as_float((unsigned)(hv >> 32)));
        }
        __syncthreads();   // fill -> compute

        // 4 gate rows for hidx: 32 cols/lane + 4-stage butterfly.
        float sums[4];
        const float* hrow = &h_lds[li * 36];
        #pragma unroll
        for (int gate = 0; gate < 4; ++gate) {
            float acc = 0.0f;
            #pragma unroll
            for (int k = 0; k < 32; k += 4) {
                const float4 h4 = *(const float4*)(hrow + k);
                acc = fmaf(wreg[gate][k],     h4.x, acc);
                acc = fmaf(wreg[gate][k + 1], h4.y, acc);
                acc = fmaf(wreg[gate][k + 2], h4.z, acc);
                acc = fmaf(wreg[gate][k + 3], h4.w, acc);
            }
            acc += __shfl_xor(acc, 1);
            acc += __shfl_xor(acc, 2);
            acc += __shfl_xor(acc, 4);
            acc += __shfl_xor(acc, 8);
            sums[gate] = acc;
        }

        float hnew = 0.0f;
        if (upd) {
            const float iv = fsig(sums[0] + xi);
            const float fv = fsig(sums[1] + xf);
            const float gv = ftanh(sums[2] + xg);
            const float ov = fsig(sums[3] + xo);
            c = fv * c + iv * gv;
            hnew = ov * ftanh(c);
            if (s == NSTEP - 1) {
                out[1 + hidx] = hnew;
                out[1 + HID + hidx] = c;
            }
        }
        // Pair adjacent h values (g,g+1) and publish with ONE atomic 8B store:
        // lane 0 stores {h[j], h[j+1]}, lane 32 stores {h[j+2], h[j+3]}.
        const float hpart = __shfl(hnew, lane + 16);   // lane0<-16, lane32<-48
        if (upd && (g & 1) == 0) {
            const unsigned long long pair =
                (unsigned long long)__float_as_uint(hnew) |
                ((unsigned long long)__float_as_uint(hpart) << 32);
            unsigned long long* dst = (unsigned long long*)
                (hseq + (size_t)(s + 1) * HID + wg * 16 + v * 4 + g);
            __hip_atomic_store(dst, pair, __ATOMIC_RELAXED, __HIP_MEMORY_SCOPE_AGENT);
        }
    }

    // Epilogue: WG 0 computes out[0] = sigmoid(fc_w . h_300 + fc_b).
    if (wg == 0) {
        const unsigned long long va =
            poll8_pipe((const float*)hseq + (size_t)NSTEP * HID + 2 * tid, SENT64);
        const float p = __uint_as_float((unsigned)va) * fc_w[2 * tid]
                      + __uint_as_float((unsigned)(va >> 32)) * fc_w[2 * tid + 1];
        __syncthreads();          // h_lds free for reuse
        h_lds[tid] = p;
        __syncthreads();
        for (int off = 128; off > 0; off >>= 1) {
            if (tid < off) h_lds[tid] += h_lds[tid + off];
            __syncthreads();
        }
        if (tid == 0) out[0] = fsig(h_lds[0] + fc_b[0]);
    }
}

extern "C" void kernel_launch(void* const* d_in, const int* in_sizes, int n_in,
                              void* d_out, int out_size, void* d_ws, size_t ws_size,
                              hipStream_t stream) {
    (void)in_sizes; (void)n_in; (void)out_size; (void)ws_size;
    const int*   x     = (const int*)d_in[0];
    const float* h0    = (const float*)d_in[1];
    const float* c0    = (const float*)d_in[2];
    const float* emb   = (const float*)d_in[3];
    const float* W_ih  = (const float*)d_in[4];
    const float* W_hh  = (const float*)d_in[5];
    const float* b_ih  = (const float*)d_in[6];
    const float* b_hh  = (const float*)d_in[7];
    const float* fc_w  = (const float*)d_in[8];
    const float* fc_b  = (const float*)d_in[9];
    float* out = (float*)d_out;
    float* ws  = (float*)d_ws;

    xproj_init_kernel<<<dim3(NRG, NSG), dim3(TPB), 0, stream>>>(
        x, h0, emb, W_ih, b_ih, b_hh, ws);
    lstm_scan_kernel<<<dim3(NWG), dim3(TPB), 0, stream>>>(
        c0, W_hh, fc_w, fc_b, ws, out);
}

// Round 7
// 820.320 us; speedup vs baseline: 1.0140x; 1.0140x over previous
//
#include <hip/hip_runtime.h>

#define EMBD 300
#define NSTEP 300
#define HID 512
#define G4 2048
#define TPB1 256
#define TPB2 512
#define NWG 32

#define TS2 15              // steps per phase-1 step-group
#define NSG 20              // step groups (20*15 = 300)
#define NRG 8               // row groups (8*256 = 2048 rows)

#define SENTINEL 0xFFC00000u              // quiet NaN: h values are always finite

// ws float layout:
//   [0 .. 614400)      : X_proj [300][2048]
//   [614400 .. +154112): HSEQ [301][512]  (h state before each step)
#define XP_SZ    (NSTEP * G4)
#define HSEQ_OFF XP_SZ

__device__ __forceinline__ float fsig(float x) { return 1.0f / (1.0f + __expf(-x)); }
__device__ __forceinline__ float ftanh(float x) {
    x = fminf(15.0f, fmaxf(-15.0f, x));
    float t = __expf(2.0f * x);
    return (t - 1.0f) / (t + 1.0f);
}

// Phase 1: X_proj[t][r] = b_ih[r]+b_hh[r] + sum_e W_ih[r][e]*emb[x[t]][e]
// Grid (NRG, NSG). rowg==0 blocks sentinel-clear HSEQ rows t0+1..t0+15;
// (0,0) also copies h0 into HSEQ[0]. Re-done every call -> replay-safe.
__global__ __launch_bounds__(TPB1) void xproj_init_kernel(
    const int* __restrict__ x, const float* __restrict__ h0,
    const float* __restrict__ emb, const float* __restrict__ W_ih,
    const float* __restrict__ b_ih, const float* __restrict__ b_hh,
    float* __restrict__ ws) {
    const int rowg = blockIdx.x;      // 0..7
    const int sg   = blockIdx.y;      // 0..19
    const int tid  = threadIdx.x;
    const int t0   = sg * TS2;
    const int r    = rowg * TPB1 + tid;

    float* hseq = ws + HSEQ_OFF;

    if (rowg == 0) {
        unsigned* hs = (unsigned*)(hseq + (size_t)(t0 + 1) * HID);
        for (int i = tid; i < TS2 * HID; i += TPB1) hs[i] = SENTINEL;
        if (sg == 0) {
            for (int i = tid; i < HID; i += TPB1) hseq[i] = h0[i];
        }
    }

    __shared__ float e_lds[TS2][EMBD];
    for (int tt = 0; tt < TS2; ++tt) {
        const float* er = emb + (long long)x[t0 + tt] * EMBD;
        for (int i = tid; i < EMBD; i += TPB1) e_lds[tt][i] = er[i];
    }
    __syncthreads();

    float acc[TS2];
    const float bsum = b_ih[r] + b_hh[r];
    #pragma unroll
    for (int tt = 0; tt < TS2; ++tt) acc[tt] = bsum;

    const float* wrow = W_ih + (size_t)r * EMBD;
    for (int e = 0; e < EMBD; e += 4) {
        const float4 w4 = *(const float4*)(wrow + e);
        #pragma unroll
        for (int tt = 0; tt < TS2; ++tt) {
            acc[tt] = fmaf(w4.x, e_lds[tt][e],     acc[tt]);
            acc[tt] = fmaf(w4.y, e_lds[tt][e + 1], acc[tt]);
            acc[tt] = fmaf(w4.z, e_lds[tt][e + 2], acc[tt]);
            acc[tt] = fmaf(w4.w, e_lds[tt][e + 3], acc[tt]);
        }
    }
    #pragma unroll
    for (int tt = 0; tt < TS2; ++tt)
        ws[(size_t)(t0 + tt) * G4 + r] = acc[tt];
}

// Phase 2: 32 WGs x 512 threads persistent dataflow scan.
// Each 32-lane group owns ONE hidx = wg*16 + (tid>>5); within the group,
// gate = (sub>>3) and 8 column-lanes x 64 cols each -> wreg[64] per thread
// (register-resident; the R1..R5 layout needed 128/thread and spilled).
// 3-stage butterfly + 3 shfl's deliver all 4 gate sums to sub==0, which
// carries c and publishes h pairs as single 8B relaxed agent-scope atomic
// stores (R1-proven visibility path). Consumers (tid<256) poll their own 8B
// slot with relaxed agent loads + s_sleep backoff (R1-proven), then fill a
// DOUBLE-BUFFERED LDS h tile: one __syncthreads per step is provably safe
// (fill@step u is ordered after all same-WG LDS reads@u-2 via the
// publish->detect data chain; distance-1 uses the other buffer).
__global__ __launch_bounds__(TPB2, 1) void lstm_scan_kernel(
    const float* __restrict__ c0, const float* __restrict__ W_hh,
    const float* __restrict__ fc_w, const float* __restrict__ fc_b,
    float* __restrict__ ws, float* __restrict__ out) {
    const int tid  = threadIdx.x;
    const int wg   = blockIdx.x;
    const int lane = tid & 63;
    const int grp  = tid >> 5;      // 0..15: hidx group within WG
    const int sub  = tid & 31;      // lane within group
    const int gate = sub >> 3;      // i,f,g,o
    const int cl   = sub & 7;       // column-lane: cols [cl*64, cl*64+64)
    const int hidx = wg * 16 + grp;

    float* hseq     = ws + HSEQ_OFF;        // [301][512]
    const float* xp = ws;                   // [300][2048]

    // Padded h tile: logical idx i lives at i + 4*(i>>6) (stride-68 rows of 64).
    __shared__ __align__(16) float h_lds[2][544];

    // wreg[k] = W_hh[(gate*HID + hidx)*HID + cl*64 + k], k in [0,64)
    float wreg[64];
    {
        const float* wr = W_hh + ((size_t)gate * HID + hidx) * HID + cl * 64;
        #pragma unroll
        for (int k = 0; k < 64; k += 4) {
            const float4 w4 = *(const float4*)(wr + k);
            wreg[k] = w4.x; wreg[k + 1] = w4.y;
            wreg[k + 2] = w4.z; wreg[k + 3] = w4.w;
        }
    }

    const bool upd = (sub == 0);
    float c = upd ? c0[hidx] : 0.0f;

    for (int s = 0; s < NSTEP; ++s) {
        // X_proj loads issued before the poll -> latency hidden under it.
        float xi = 0.f, xf = 0.f, xg = 0.f, xo = 0.f;
        if (upd) {
            const float* xpt = xp + (size_t)s * G4 + hidx;
            xi = xpt[0]; xf = xpt[HID]; xg = xpt[2 * HID]; xo = xpt[3 * HID];
        }

        // tid<256: poll own 8B slot of HSEQ[s], fill this step's LDS buffer.
        if (tid < 256) {
            const unsigned long long* slot =
                (const unsigned long long*)(hseq + (size_t)s * HID) + tid;
            unsigned long long hv = __hip_atomic_load(slot, __ATOMIC_RELAXED,
                                                      __HIP_MEMORY_SCOPE_AGENT);
            while ((unsigned)hv == SENTINEL || (unsigned)(hv >> 32) == SENTINEL) {
                __builtin_amdgcn_s_sleep(1);
                hv = __hip_atomic_load(slot, __ATOMIC_RELAXED,
                                       __HIP_MEMORY_SCOPE_AGENT);
            }
            const int i0 = 2 * tid + ((tid >> 5) << 2);
            *(float2*)&h_lds[s & 1][i0] =
                make_float2(__uint_as_float((unsigned)hv),
                            __uint_as_float((unsigned)(hv >> 32)));
        }
        __syncthreads();   // fill -> compute (single barrier per step)

        // 64-col partial dot, conflict-free stride-68 rows.
        float acc = 0.0f;
        const float* hrow = &h_lds[s & 1][cl * 68];
        #pragma unroll
        for (int k = 0; k < 64; k += 4) {
            const float4 h4 = *(const float4*)(hrow + k);
            acc = fmaf(wreg[k],     h4.x, acc);
            acc = fmaf(wreg[k + 1], h4.y, acc);
            acc = fmaf(wreg[k + 2], h4.z, acc);
            acc = fmaf(wreg[k + 3], h4.w, acc);
        }
        acc += __shfl_xor(acc, 1);
        acc += __shfl_xor(acc, 2);
        acc += __shfl_xor(acc, 4);

        // Gather the 4 gate sums of this 32-group (uniform, no divergence).
        const int base = lane & ~31;
        const float gi = __shfl(acc, base + 0);
        const float gf = __shfl(acc, base + 8);
        const float gg = __shfl(acc, base + 16);
        const float go = __shfl(acc, base + 24);

        float hnew = 0.0f;
        if (upd) {
            const float iv = fsig(gi + xi);
            const float fv = fsig(gf + xf);
            const float gv = ftanh(gg + xg);
            const float ov = fsig(go + xo);
            c = fv * c + iv * gv;
            hnew = ov * ftanh(c);
        }
        // Pair the wave's two hidx values (lane0 <- lane32) and publish with
        // ONE 8B relaxed agent-scope atomic store (slot flips atomically).
        const float hhi = __shfl(hnew, (lane + 32) & 63);
        if (lane == 0) {
            const unsigned long long pair =
                (unsigned long long)__float_as_uint(hnew) |
                ((unsigned long long)__float_as_uint(hhi) << 32);
            unsigned long long* dst =
                (unsigned long long*)(hseq + (size_t)(s + 1) * HID + hidx);
            __hip_atomic_store(dst, pair, __ATOMIC_RELAXED,
                               __HIP_MEMORY_SCOPE_AGENT);
        }
        if (upd && s == NSTEP - 1) {
            out[1 + hidx] = hnew;
            out[1 + HID + hidx] = c;
        }
    }

    // Epilogue: WG 0 computes out[0] = sigmoid(fc_w . h_300 + fc_b).
    if (wg == 0) {
        __shared__ float red[256];
        if (tid < 256) {
            const unsigned long long* slot =
                (const unsigned long long*)(hseq + (size_t)NSTEP * HID) + tid;
            unsigned long long hv = __hip_atomic_load(slot, __ATOMIC_RELAXED,
                                                      __HIP_MEMORY_SCOPE_AGENT);
            while ((unsigned)hv == SENTINEL || (unsigned)(hv >> 32) == SENTINEL) {
                __builtin_amdgcn_s_sleep(1);
                hv = __hip_atomic_load(slot, __ATOMIC_RELAXED,
                                       __HIP_MEMORY_SCOPE_AGENT);
            }
            red[tid] = __uint_as_float((unsigned)hv) * fc_w[2 * tid]
                     + __uint_as_float((unsigned)(hv >> 32)) * fc_w[2 * tid + 1];
        }
        __syncthreads();
        for (int off = 128; off > 0; off >>= 1) {
            if (tid < off) red[tid] += red[tid + off];
            __syncthreads();
        }
        if (tid == 0) out[0] = fsig(red[0] + fc_b[0]);
    }
}

extern "C" void kernel_launch(void* const* d_in, const int* in_sizes, int n_in,
                              void* d_out, int out_size, void* d_ws, size_t ws_size,
                              hipStream_t stream) {
    (void)in_sizes; (void)n_in; (void)out_size; (void)ws_size;
    const int*   x     = (const int*)d_in[0];
    const float* h0    = (const float*)d_in[1];
    const float* c0    = (const float*)d_in[2];
    const float* emb   = (const float*)d_in[3];
    const float* W_ih  = (const float*)d_in[4];
    const float* W_hh  = (const float*)d_in[5];
    const float* b_ih  = (const float*)d_in[6];
    const float* b_hh  = (const float*)d_in[7];
    const float* fc_w  = (const float*)d_in[8];
    const float* fc_b  = (const float*)d_in[9];
    float* out = (float*)d_out;
    float* ws  = (float*)d_ws;

    xproj_init_kernel<<<dim3(NRG, NSG), dim3(TPB1), 0, stream>>>(
        x, h0, emb, W_ih, b_ih, b_hh, ws);
    lstm_scan_kernel<<<dim3(NWG), dim3(TPB2), 0, stream>>>(
        c0, W_hh, fc_w, fc_b, ws, out);
}

// Round 8
// 699.236 us; speedup vs baseline: 1.1896x; 1.1732x over previous
//
#include <hip/hip_runtime.h>

#define EMBD 300
#define NSTEP 300
#define HID 512
#define G4 2048
#define TPB 256
#define NWG 32

#define TS2 15              // steps per phase-1 step-group
#define NSG 20              // step groups (20*15 = 300)
#define NRG 8               // row groups (8*256 = 2048 rows)

#define SENTINEL 0xFFC00000u              // quiet NaN: h values are always finite

// ws float layout:
//   [0 .. 614400)      : X_proj [300][2048]
//   [614400 .. +154112): HSEQ [301][512]  (h state before each step)
#define XP_SZ    (NSTEP * G4)
#define HSEQ_OFF XP_SZ

__device__ __forceinline__ float fsig(float x) { return 1.0f / (1.0f + __expf(-x)); }
__device__ __forceinline__ float ftanh(float x) {
    x = fminf(15.0f, fmaxf(-15.0f, x));
    float t = __expf(2.0f * x);
    return (t - 1.0f) / (t + 1.0f);
}

// Phase 1: X_proj[t][r] = b_ih[r]+b_hh[r] + sum_e W_ih[r][e]*emb[x[t]][e]
// Grid (NRG, NSG). rowg==0 blocks sentinel-clear HSEQ rows t0+1..t0+15;
// (0,0) also copies h0 into HSEQ[0]. Re-done every call -> replay-safe.
__global__ __launch_bounds__(TPB) void xproj_init_kernel(
    const int* __restrict__ x, const float* __restrict__ h0,
    const float* __restrict__ emb, const float* __restrict__ W_ih,
    const float* __restrict__ b_ih, const float* __restrict__ b_hh,
    float* __restrict__ ws) {
    const int rowg = blockIdx.x;      // 0..7
    const int sg   = blockIdx.y;      // 0..19
    const int tid  = threadIdx.x;
    const int t0   = sg * TS2;
    const int r    = rowg * TPB + tid;

    float* hseq = ws + HSEQ_OFF;

    if (rowg == 0) {
        unsigned* hs = (unsigned*)(hseq + (size_t)(t0 + 1) * HID);
        for (int i = tid; i < TS2 * HID; i += TPB) hs[i] = SENTINEL;
        if (sg == 0) {
            for (int i = tid; i < HID; i += TPB) hseq[i] = h0[i];
        }
    }

    __shared__ float e_lds[TS2][EMBD];
    for (int tt = 0; tt < TS2; ++tt) {
        const float* er = emb + (long long)x[t0 + tt] * EMBD;
        for (int i = tid; i < EMBD; i += TPB) e_lds[tt][i] = er[i];
    }
    __syncthreads();

    float acc[TS2];
    const float bsum = b_ih[r] + b_hh[r];
    #pragma unroll
    for (int tt = 0; tt < TS2; ++tt) acc[tt] = bsum;

    const float* wrow = W_ih + (size_t)r * EMBD;
    for (int e = 0; e < EMBD; e += 4) {
        const float4 w4 = *(const float4*)(wrow + e);
        #pragma unroll
        for (int tt = 0; tt < TS2; ++tt) {
            acc[tt] = fmaf(w4.x, e_lds[tt][e],     acc[tt]);
            acc[tt] = fmaf(w4.y, e_lds[tt][e + 1], acc[tt]);
            acc[tt] = fmaf(w4.z, e_lds[tt][e + 2], acc[tt]);
            acc[tt] = fmaf(w4.w, e_lds[tt][e + 3], acc[tt]);
        }
    }
    #pragma unroll
    for (int tt = 0; tt < TS2; ++tt)
        ws[(size_t)(t0 + tt) * G4 + r] = acc[tt];
}

// Phase 2: 32 WGs x 256 threads persistent dataflow scan.
// Group (v,g) (16 lanes) owns hidx = wg*16 + v*4 + g, ALL 4 gates: lane li
// holds wreg[4][32] = W_hh[gate*512+hidx][li*32 .. +32) — PINNED into VGPRs
// via opaque asm so the compiler cannot sink the loads into the s-loop
// (R1/R6 counter evidence: it silently re-streamed W_hh from L2 every step).
// Only wave 0 polls HSEQ[s] (64 lanes x 32B covers all 512 floats) ->
// 4x fewer coherent poll transactions. LDS h is double-buffered; one
// __syncthreads per step is race-free (distance-1 uses the other buffer;
// distance-2 reuse is ordered through own-WG publish -> global detect chain).
__global__ __launch_bounds__(TPB, 1) void lstm_scan_kernel(
    const float* __restrict__ c0, const float* __restrict__ W_hh,
    const float* __restrict__ fc_w, const float* __restrict__ fc_b,
    float* __restrict__ ws, float* __restrict__ out) {
    const int tid  = threadIdx.x;
    const int wg   = blockIdx.x;
    const int v    = tid >> 6;     // wave id
    const int lane = tid & 63;
    const int g    = lane >> 4;    // group within wave
    const int li   = lane & 15;    // lane within group (column split)
    const int hidx = wg * 16 + v * 4 + g;

    float* hseq     = ws + HSEQ_OFF;        // [301][512]
    const float* xp = ws;                   // [300][2048]

    // Padded tile: logical col c lives at c + 4*(c>>6) (stride-68 blocks of 64).
    __shared__ __align__(16) float h_lds[2][544];

    // wreg[gate][k] = W_hh[(gate*HID + hidx)*HID + li*32 + k]
    float wreg[4][32];
    #pragma unroll
    for (int gate = 0; gate < 4; ++gate) {
        const float* wr = W_hh + ((size_t)gate * HID + hidx) * HID + li * 32;
        #pragma unroll
        for (int k = 0; k < 32; k += 4) {
            const float4 w4 = *(const float4*)(wr + k);
            wreg[gate][k] = w4.x; wreg[gate][k + 1] = w4.y;
            wreg[gate][k + 2] = w4.z; wreg[gate][k + 3] = w4.w;
        }
    }
    // Pin every weight into a VGPR: opaque asm output can't be re-derived
    // from the W_hh loads, so they cannot be sunk into the loop.
    #pragma unroll
    for (int gate = 0; gate < 4; ++gate)
        #pragma unroll
        for (int k = 0; k < 32; ++k)
            asm volatile("" : "+v"(wreg[gate][k]));

    const bool upd = (li == 0);
    float c = upd ? c0[hidx] : 0.0f;

    for (int s = 0; s < NSTEP; ++s) {
        // X_proj loads issued before the poll/barrier -> latency hidden.
        float xi = 0.f, xf = 0.f, xg = 0.f, xo = 0.f;
        if (upd) {
            const float* xpt = xp + (size_t)s * G4 + hidx;
            xi = xpt[0]; xf = xpt[HID]; xg = xpt[2 * HID]; xo = xpt[3 * HID];
        }

        // Wave 0: poll 32B/lane (4 x 8B slots) of HSEQ[s], fill LDS buffer.
        if (v == 0) {
            const unsigned long long* slot =
                (const unsigned long long*)(hseq + (size_t)s * HID) + lane * 4;
            unsigned long long a0, a1, a2, a3;
            for (;;) {
                a0 = __hip_atomic_load(slot + 0, __ATOMIC_RELAXED, __HIP_MEMORY_SCOPE_AGENT);
                a1 = __hip_atomic_load(slot + 1, __ATOMIC_RELAXED, __HIP_MEMORY_SCOPE_AGENT);
                a2 = __hip_atomic_load(slot + 2, __ATOMIC_RELAXED, __HIP_MEMORY_SCOPE_AGENT);
                a3 = __hip_atomic_load(slot + 3, __ATOMIC_RELAXED, __HIP_MEMORY_SCOPE_AGENT);
                const bool bad =
                    (unsigned)a0 == SENTINEL || (unsigned)(a0 >> 32) == SENTINEL ||
                    (unsigned)a1 == SENTINEL || (unsigned)(a1 >> 32) == SENTINEL ||
                    (unsigned)a2 == SENTINEL || (unsigned)(a2 >> 32) == SENTINEL ||
                    (unsigned)a3 == SENTINEL || (unsigned)(a3 >> 32) == SENTINEL;
                if (!bad) break;
                __builtin_amdgcn_s_sleep(1);
            }
            const int base = lane * 8 + ((lane >> 3) << 2);  // padded col idx
            float* dst = &h_lds[s & 1][base];
            *(float2*)(dst + 0) = make_float2(__uint_as_float((unsigned)a0),
                                              __uint_as_float((unsigned)(a0 >> 32)));
            *(float2*)(dst + 2) = make_float2(__uint_as_float((unsigned)a1),
                                              __uint_as_float((unsigned)(a1 >> 32)));
            *(float2*)(dst + 4) = make_float2(__uint_as_float((unsigned)a2),
                                              __uint_as_float((unsigned)(a2 >> 32)));
            *(float2*)(dst + 6) = make_float2(__uint_as_float((unsigned)a3),
                                              __uint_as_float((unsigned)(a3 >> 32)));
        }
        __syncthreads();   // fill -> compute (single barrier per step)

        // 4 gate rows for hidx: 32 cols/lane + 4-stage butterfly (16-lane).
        float sums[4];
        const float* hrow = &h_lds[s & 1][li * 32 + ((li >> 1) << 2)];
        #pragma unroll
        for (int gate = 0; gate < 4; ++gate) {
            float acc = 0.0f;
            #pragma unroll
            for (int k = 0; k < 32; k += 4) {
                const float4 h4 = *(const float4*)(hrow + k);
                acc = fmaf(wreg[gate][k],     h4.x, acc);
                acc = fmaf(wreg[gate][k + 1], h4.y, acc);
                acc = fmaf(wreg[gate][k + 2], h4.z, acc);
                acc = fmaf(wreg[gate][k + 3], h4.w, acc);
            }
            acc += __shfl_xor(acc, 1);
            acc += __shfl_xor(acc, 2);
            acc += __shfl_xor(acc, 4);
            acc += __shfl_xor(acc, 8);
            sums[gate] = acc;
        }

        float hnew = 0.0f;
        if (upd) {
            const float iv = fsig(sums[0] + xi);
            const float fv = fsig(sums[1] + xf);
            const float gv = ftanh(sums[2] + xg);
            const float ov = fsig(sums[3] + xo);
            c = fv * c + iv * gv;
            hnew = ov * ftanh(c);
            if (s == NSTEP - 1) {
                out[1 + hidx] = hnew;
                out[1 + HID + hidx] = c;
            }
        }
        // Pair adjacent h values (lane0 <- lane16, lane32 <- lane48) and
        // publish with ONE 8B relaxed agent-scope atomic store per pair.
        const float hpart = __shfl(hnew, lane + 16);
        if ((lane & 31) == 0) {   // lanes 0 and 32
            const unsigned long long pair =
                (unsigned long long)__float_as_uint(hnew) |
                ((unsigned long long)__float_as_uint(hpart) << 32);
            unsigned long long* dst = (unsigned long long*)
                (hseq + (size_t)(s + 1) * HID + wg * 16 + v * 4 + (lane >> 4));
            __hip_atomic_store(dst, pair, __ATOMIC_RELAXED, __HIP_MEMORY_SCOPE_AGENT);
        }
    }

    // Epilogue: WG 0 computes out[0] = sigmoid(fc_w . h_300 + fc_b).
    if (wg == 0) {
        __shared__ float red[256];
        const unsigned long long* slot =
            (const unsigned long long*)(hseq + (size_t)NSTEP * HID) + tid;
        unsigned long long hv = __hip_atomic_load(slot, __ATOMIC_RELAXED,
                                                  __HIP_MEMORY_SCOPE_AGENT);
        while ((unsigned)hv == SENTINEL || (unsigned)(hv >> 32) == SENTINEL) {
            __builtin_amdgcn_s_sleep(1);
            hv = __hip_atomic_load(slot, __ATOMIC_RELAXED,
                                   __HIP_MEMORY_SCOPE_AGENT);
        }
        red[tid] = __uint_as_float((unsigned)hv) * fc_w[2 * tid]
                 + __uint_as_float((unsigned)(hv >> 32)) * fc_w[2 * tid + 1];
        __syncthreads();
        for (int off = 128; off > 0; off >>= 1) {
            if (tid < off) red[tid] += red[tid + off];
            __syncthreads();
        }
        if (tid == 0) out[0] = fsig(red[0] + fc_b[0]);
    }
}

extern "C" void kernel_launch(void* const* d_in, const int* in_sizes, int n_in,
                              void* d_out, int out_size, void* d_ws, size_t ws_size,
                              hipStream_t stream) {
    (void)in_sizes; (void)n_in; (void)out_size; (void)ws_size;
    const int*   x     = (const int*)d_in[0];
    const float* h0    = (const float*)d_in[1];
    const float* c0    = (const float*)d_in[2];
    const float* emb   = (const float*)d_in[3];
    const float* W_ih  = (const float*)d_in[4];
    const float* W_hh  = (const float*)d_in[5];
    const float* b_ih  = (const float*)d_in[6];
    const float* b_hh  = (const float*)d_in[7];
    const float* fc_w  = (const float*)d_in[8];
    const float* fc_b  = (const float*)d_in[9];
    float* out = (float*)d_out;
    float* ws  = (float*)d_ws;

    xproj_init_kernel<<<dim3(NRG, NSG), dim3(TPB), 0, stream>>>(
        x, h0, emb, W_ih, b_ih, b_hh, ws);
    lstm_scan_kernel<<<dim3(NWG), dim3(TPB), 0, stream>>>(
        c0, W_hh, fc_w, fc_b, ws, out);
}